// Round 7
// baseline (335.423 us; speedup 1.0000x reference)
//
#include <hip/hip_runtime.h>
#include <hip/hip_bf16.h>
#include <stdint.h>

// ---------------------------------------------------------------------------
// EquivariantAttention on MI355X.  Dtype-adaptive (bf16 or fp32 inputs).
// R6: kB scalar-bf16, no eaS; 316us total, kB 112us @ VALUBusy 40%.
// R7: (1) kQK: q staged in LDS + kT4 packed layout -> 1 float4 VMEM per 4 K-elems
//     (old: 5 unscalarizable VMEM per 4 FMAs);
//     (2) kB: AsndS removed from LDS (direct global uint4 reads) ->
//     LDS 37.4->18.7KB -> ~2x resident waves to hide stalls.
// ---------------------------------------------------------------------------

#define NNODES 512
#define NDIM   480

// ws layout (4-byte word offsets)
#define QS_OFF    0u         // 512*480 f32 q, per-head layout, CG*ATTN folded
#define KT_OFF    245760u    // k packed: [h(8)][j4(15)][n(512)][4] f32
#define VB_OFF    491520u    // 512*480 f32 v, output-irrep (final) layout
#define ARE_OFF   737280u    // 512*288 u32 (bf16 pairs over o): [n][mi(9)][oc(32)]
#define ASN_OFF   884736u    // 512*288 u32
#define WF_OFF    1032192u   // 8192 f32: W1a[32][64]@0, W2T[64][64]@2048, W3[64][8]@6144, b1@6656, b2@6720, b3@6784
#define FLAG_OFF  1040384u   // flag[0] = 1 if inputs fp32, 0 if bf16
#define L_OFF     1040448u   // 512*512*8 f32 logits -> weights (in-place)

__device__ __forceinline__ float bf2f(uint16_t u) {
    return __uint_as_float(((uint32_t)u) << 16);
}
__device__ __forceinline__ uint16_t f2bf(float f) {
    union { __hip_bfloat16 h; uint16_t u; } cv;
    cv.h = __float2bfloat16(f);
    return cv.u;
}
__device__ __forceinline__ float ldin(const void* p, size_t i, int f32) {
    return f32 ? ((const float*)p)[i] : bf2f(((const uint16_t*)p)[i]);
}
// tanh(x) = 1 - 2/(exp(2x)+1)
__device__ __forceinline__ float ftanh(float x) {
    float e = __builtin_amdgcn_exp2f(x * 2.885390081777927f);
    return 1.0f - 2.0f * __builtin_amdgcn_rcpf(e + 1.0f);
}

// ------------------------------------------------- dtype detector
__global__ __launch_bounds__(64) void kDet(const uint32_t* __restrict__ nf,
                                           int* __restrict__ flag)
{
    int t = threadIdx.x;
    uint32_t x = nf[64 + t];
    int e = (x >> 7) & 0xff;
    int good = (x != 0u) && (e >= 100) && (e <= 140);
    unsigned long long m = __ballot(good);
    if (t == 0) flag[0] = (__popcll(m) < 32) ? 1 : 0;
}

// ---------------------------------------------------------------- weights prep
__global__ __launch_bounds__(256) void kW(
    const void* __restrict__ mW1, const void* __restrict__ mb1,
    const void* __restrict__ mW2, const void* __restrict__ mb2,
    const void* __restrict__ mW3, const void* __restrict__ mb3,
    float* __restrict__ Wf, const int* __restrict__ flagp)
{
    const int f32 = flagp[0];
    const int t = threadIdx.x;
    for (int i = t; i < 2048; i += 256) Wf[i] = ldin(mW1, i, f32);      // W1a rows 0..31
    for (int i = t; i < 4096; i += 256) {                               // W2 transposed
        int o2 = i >> 6, ii = i & 63;
        Wf[2048 + i] = ldin(mW2, ii * 64 + o2, f32);
    }
    for (int i = t; i < 512; i += 256) Wf[6144 + i] = ldin(mW3, i, f32);
    if (t < 64) Wf[6656 + t] = ldin(mb1, t, f32);
    if (t < 64) Wf[6720 + t] = ldin(mb2, t, f32);
    if (t < 8)  Wf[6784 + t] = ldin(mb3, t, f32);
}

// ------------------------------------------------- per-node precompute
__global__ __launch_bounds__(256) void kA(
    const void* __restrict__ nfu,
    const void* __restrict__ Wq0, const void* __restrict__ Wq1, const void* __restrict__ Wq2,
    const void* __restrict__ Wk0, const void* __restrict__ Wk1, const void* __restrict__ Wk2,
    const void* __restrict__ Wv0, const void* __restrict__ Wv1, const void* __restrict__ Wv2,
    const void* __restrict__ mW1,
    float* __restrict__ qS, float* __restrict__ kT4, float* __restrict__ vB,
    uint32_t* __restrict__ ArecG, uint32_t* __restrict__ AsndG,
    const int* __restrict__ flagp)
{
    const int f32 = flagp[0];
    const int n = blockIdx.x, t = threadIdx.x;
    __shared__ float nfs[480];
    for (int i = t; i < 480; i += 256) nfs[i] = ldin(nfu, (size_t)n * 480 + i, f32);
    __syncthreads();

    const float e3n0 = 0.08838834764831845f;  // 1/sqrt(128)
    const float e3n1 = 0.125f;                // 1/sqrt(64)
    const float e3n2 = 0.17677669529663687f;  // 1/sqrt(32)
    const float cg0 = 1.0f, cg1 = 0.5773502691896258f, cg2 = 0.4472135954999579f;
    const float attn = 0.1889822365046136f;   // 1/sqrt(28)

    // q/k/v: 3 kinds x 480 outputs
    for (int idx = t; idx < 1440; idx += 256) {
        int kind = idx / 480, rem = idx - kind * 480;
        int l, o, m, mul, d, off, am, qoff;
        if (rem < 128)      { l = 0; o = rem;            m = 0;         mul = 128; d = 1; off = 0;   am = 16; qoff = 0;  }
        else if (rem < 320) { l = 1; int x = rem - 128;  o = x / 3; m = x - o * 3; mul = 64;  d = 3; off = 128; am = 8;  qoff = 16; }
        else                { l = 2; int x = rem - 320;  o = x / 5; m = x - o * 5; mul = 32;  d = 5; off = 320; am = 4;  qoff = 40; }
        const void* W;
        if (kind == 0)      W = (l == 0 ? Wq0 : l == 1 ? Wq1 : Wq2);
        else if (kind == 1) W = (l == 0 ? Wk0 : l == 1 ? Wk1 : Wk2);
        else                W = (l == 0 ? Wv0 : l == 1 ? Wv1 : Wv2);
        float acc = 0.f;
        if (f32) {
            const float* W32 = (const float*)W;
            for (int i = 0; i < mul; ++i) acc += nfs[off + i * d + m] * W32[i * mul + o];
        } else {
            const uint16_t* W16 = (const uint16_t*)W;
            for (int i = 0; i < mul; ++i) acc += nfs[off + i * d + m] * bf2f(W16[i * mul + o]);
        }
        float e3n = (l == 0 ? e3n0 : l == 1 ? e3n1 : e3n2);
        float cg  = (l == 0 ? cg0 : l == 1 ? cg1 : cg2);
        if (kind == 2) {
            vB[(size_t)n * 480 + rem] = acc * e3n;                 // final output layout
        } else {
            int hh = o / am, a = o - hh * am;
            int j = qoff + a * d + m;                              // 0..59 within head
            if (kind == 0) qS[(size_t)n * 480 + hh * 60 + j] = acc * (e3n * cg * attn);
            else           kT4[((size_t)(hh * 15 + (j >> 2)) * 512 + n) * 4 + (j & 3)] = acc * e3n;
        }
    }

    // Arec/Asnd: 2 kinds x 9 mi x 32 o-pairs, packed bf16: [n][mi(9)][oc(32)]
    for (int idx = t; idx < 576; idx += 256) {
        int kind2 = idx / 288, rem = idx - kind2 * 288;
        int mi = rem >> 5, oc = rem & 31;
        int l, m;
        if (mi == 0)     { l = 0; m = 0; }
        else if (mi < 4) { l = 1; m = mi - 1; }
        else             { l = 2; m = mi - 4; }
        int mul = (l == 0 ? 128 : l == 1 ? 64 : 32);
        int d = 2 * l + 1;
        int off = (l == 0 ? 0 : l == 1 ? 128 : 320);
        int base = (kind2 == 0) ? (l == 0 ? 32 : l == 1 ? 160 : 224)
                                : (l == 0 ? 256 : l == 1 ? 384 : 448);
        float a0 = 0.f, a1 = 0.f;
        if (f32) {
            const float* wp = (const float*)mW1 + (size_t)base * 64 + 2 * oc;
            for (int i = 0; i < mul; ++i) {
                float nv = nfs[off + i * d + m];
                a0 += nv * wp[i * 64];
                a1 += nv * wp[i * 64 + 1];
            }
        } else {
            const uint16_t* wp = (const uint16_t*)mW1 + (size_t)base * 64 + 2 * oc;
            for (int i = 0; i < mul; ++i) {
                float nv = nfs[off + i * d + m];
                a0 += nv * bf2f(wp[i * 64]);
                a1 += nv * bf2f(wp[i * 64 + 1]);
            }
        }
        float cg = (l == 0 ? cg0 : l == 1 ? cg1 : cg2);
        a0 *= cg; a1 *= cg;
        uint32_t pk = ((uint32_t)f2bf(a1) << 16) | (uint32_t)f2bf(a0);
        (kind2 ? AsndG : ArecG)[(size_t)n * 288 + mi * 32 + oc] = pk;
    }
}

// ------------------------------------------------- q.k logits -> L
// lane = sender; q tile (16 r x 4 h) staged in LDS (broadcast reads);
// k via kT4 float4 loads (4 K-elems per VMEM inst).
__global__ __launch_bounds__(256) void kQK(
    const float* __restrict__ qS, const float* __restrict__ kT4,
    float* __restrict__ L)
{
    __shared__ float qL[16 * 240];        // [r16][(h-hb)*60 + j]
    const int t = threadIdx.x;
    const int lane = t & 63, wave = t >> 6;
    const int s0 = blockIdx.x * 64, r0 = blockIdx.y * 16, hb = blockIdx.z * 4;

    {
        float4* qL4 = reinterpret_cast<float4*>(qL);
        for (int i = t; i < 960; i += 256) {
            int rr = i / 60, c4 = i - rr * 60;
            qL4[i] = reinterpret_cast<const float4*>(
                         qS + (size_t)(r0 + rr) * 480 + hb * 60)[c4];
        }
    }
    __syncthreads();

    const int s = s0 + lane;
    const int rw = wave * 4;                         // 4 receivers per wave
    const float4* qL4 = reinterpret_cast<const float4*>(qL);
    const float4* k4  = reinterpret_cast<const float4*>(kT4);

    float acc[16];                                   // [r(4)][h4(4)]
    #pragma unroll
    for (int i = 0; i < 16; ++i) acc[i] = 0.f;

    #pragma unroll
    for (int h4 = 0; h4 < 4; ++h4) {
        const int h = hb + h4;
        #pragma unroll 3
        for (int j4 = 0; j4 < 15; ++j4) {
            float4 kv = k4[(size_t)(h * 15 + j4) * 512 + s];
            #pragma unroll
            for (int r = 0; r < 4; ++r) {
                float4 qv = qL4[(rw + r) * 60 + h4 * 15 + j4];   // wave-broadcast
                acc[r * 4 + h4] += qv.x * kv.x + qv.y * kv.y + qv.z * kv.z + qv.w * kv.w;
            }
        }
    }
    #pragma unroll
    for (int r = 0; r < 4; ++r) {
        float4 v = make_float4(acc[r * 4], acc[r * 4 + 1], acc[r * 4 + 2], acc[r * 4 + 3]);
        float* Lp = L + ((((size_t)(r0 + rw + r)) << 9) + s) * 8 + hb;
        *reinterpret_cast<float4*>(Lp) = v;
    }
}

// ------------------------------------------------- edge MLP (the hot kernel)
// 16x16 edge tile / 256 threads; Arec in LDS; Asnd + ea direct from global.
__global__ __launch_bounds__(256) void kB(
    const void* __restrict__ eaG, const void* __restrict__ shG,
    const uint32_t* __restrict__ ArecG, const uint32_t* __restrict__ AsndG,
    const float* __restrict__ Wf, float* __restrict__ L,
    const int* __restrict__ flagp)
{
    __shared__ uint32_t ArecS[16 * 292];   // bf16 pairs, row stride 292 dw
    const int f32 = flagp[0];
    const int t = threadIdx.x;
    const int s0 = blockIdx.x * 16, r0 = blockIdx.y * 16;

    for (int i = t; i < 16 * 288; i += 256) {
        int row = i / 288, c = i - row * 288;
        ArecS[row * 292 + c] = ArecG[(size_t)(r0 + row) * 288 + c];
    }

    const int rl = t >> 4, sl = t & 15;
    const int r = r0 + rl, s = s0 + sl;
    const size_t eidx = (((size_t)r) << 9) + s;

    // ea: 32 channels as 16 packed bf16 pairs, loaded directly from global
    uint32_t eaR[16];
    if (f32) {
        const float4* ep = reinterpret_cast<const float4*>((const float*)eaG + eidx * 32);
        #pragma unroll
        for (int i = 0; i < 8; ++i) {
            float4 v = ep[i];
            eaR[2 * i]     = ((uint32_t)f2bf(v.y) << 16) | (uint32_t)f2bf(v.x);
            eaR[2 * i + 1] = ((uint32_t)f2bf(v.w) << 16) | (uint32_t)f2bf(v.z);
        }
    } else {
        const uint4* ep = reinterpret_cast<const uint4*>((const uint32_t*)eaG + eidx * 16);
        #pragma unroll
        for (int i = 0; i < 4; ++i) {
            uint4 v = ep[i];
            eaR[4 * i] = v.x; eaR[4 * i + 1] = v.y; eaR[4 * i + 2] = v.z; eaR[4 * i + 3] = v.w;
        }
    }

    float sh0, sh1, sh2, sh3, sh4, sh5, sh6, sh7, sh8;
    {
        const size_t sb = eidx * 9;
        if (f32) {
            const float* shp = (const float*)shG + sb;
            sh0 = shp[0]; sh1 = shp[1]; sh2 = shp[2]; sh3 = shp[3]; sh4 = shp[4];
            sh5 = shp[5]; sh6 = shp[6]; sh7 = shp[7]; sh8 = shp[8];
        } else {
            const uint16_t* shp = (const uint16_t*)shG + sb;
            sh0 = bf2f(shp[0]); sh1 = bf2f(shp[1]); sh2 = bf2f(shp[2]);
            sh3 = bf2f(shp[3]); sh4 = bf2f(shp[4]); sh5 = bf2f(shp[5]);
            sh6 = bf2f(shp[6]); sh7 = bf2f(shp[7]); sh8 = bf2f(shp[8]);
        }
    }

    float h[64];
    #pragma unroll
    for (int o = 0; o < 64; ++o) h[o] = Wf[6656 + o];   // b1

    __syncthreads();   // ArecS ready

    // sh-mix: h[o] += sh[mi]*(Arec[r][mi][o] + Asnd[s][mi][o])
    {
        const int rb = rl * 292;
        const uint4* As4 = reinterpret_cast<const uint4*>(AsndG + (size_t)s * 288);
        #pragma unroll 1
        for (int mi = 0; mi < 9; ++mi) {
            float shv = sh0;
            shv = (mi == 1) ? sh1 : shv;  shv = (mi == 2) ? sh2 : shv;
            shv = (mi == 3) ? sh3 : shv;  shv = (mi == 4) ? sh4 : shv;
            shv = (mi == 5) ? sh5 : shv;  shv = (mi == 6) ? sh6 : shv;
            shv = (mi == 7) ? sh7 : shv;  shv = (mi == 8) ? sh8 : shv;
            const uint4* Ar4 = reinterpret_cast<const uint4*>(ArecS + rb + mi * 32);
            #pragma unroll
            for (int v = 0; v < 8; ++v) {
                uint4 pa = Ar4[v];
                uint4 pb = As4[mi * 8 + v];
                const uint32_t pas[4] = {pa.x, pa.y, pa.z, pa.w};
                const uint32_t pbs[4] = {pb.x, pb.y, pb.z, pb.w};
                #pragma unroll
                for (int k = 0; k < 4; ++k) {
                    int o = 8 * v + 2 * k;
                    float a0 = __uint_as_float(pas[k] << 16);
                    float b0 = __uint_as_float(pbs[k] << 16);
                    float a1 = __uint_as_float(pas[k] & 0xffff0000u);
                    float b1 = __uint_as_float(pbs[k] & 0xffff0000u);
                    h[o]     += shv * (a0 + b0);
                    h[o + 1] += shv * (a1 + b1);
                }
            }
        }
    }

    // edge_attr part: h[o] += ea[c]*W1a[c][o], weights wave-uniform (s_load)
    {
        #pragma unroll 1
        for (int cd = 0; cd < 16; ++cd) {
            uint32_t p = eaR[cd];
            float e0 = __uint_as_float(p << 16);
            float e1 = __uint_as_float(p & 0xffff0000u);
            const float* w0 = Wf + (2 * cd) * 64;
            #pragma unroll
            for (int o = 0; o < 64; ++o) h[o] += e0 * w0[o];
            #pragma unroll
            for (int o = 0; o < 64; ++o) h[o] += e1 * w0[64 + o];
        }
    }

    #pragma unroll
    for (int o = 0; o < 64; ++o) h[o] = ftanh(h[o]);

    // layer 2 (rolled over o2, h1 in regs) with fused layer-3 accumulation
    float ew[8];
    #pragma unroll
    for (int hh = 0; hh < 8; ++hh) ew[hh] = Wf[6784 + hh];  // b3
    #pragma unroll 1
    for (int o2 = 0; o2 < 64; ++o2) {
        const float* w2 = Wf + 2048 + o2 * 64;              // W2T row (uniform)
        float ac0 = Wf[6720 + o2], ac1 = 0.f;
        #pragma unroll
        for (int i = 0; i < 64; i += 2) {
            ac0 += h[i] * w2[i];
            ac1 += h[i + 1] * w2[i + 1];
        }
        float t2 = ftanh(ac0 + ac1);
        const float* w3 = Wf + 6144 + o2 * 8;
        #pragma unroll
        for (int hh = 0; hh < 8; ++hh) ew[hh] += t2 * w3[hh];
    }

    float* Lp = L + eidx * 8;
    #pragma unroll
    for (int hh = 0; hh < 8; ++hh) Lp[hh] += ew[hh];       // QK wrote logits first
}

// ------------------------------------------------- softmax over senders (in place)
__global__ __launch_bounds__(256) void kSM(float* __restrict__ L)
{
    __shared__ float Ls[4096];
    __shared__ float sinv[8];
    const int r = blockIdx.x, t = threadIdx.x;
    float* Lr = L + (((size_t)r) << 12);
    for (int i = t; i < 4096; i += 256) Ls[i] = Lr[i];
    __syncthreads();
    const int hh = t >> 5, lane = t & 31;
    float mx = -1e30f;
    #pragma unroll
    for (int k = 0; k < 16; ++k) mx = fmaxf(mx, Ls[(lane + (k << 5)) * 8 + hh]);
    #pragma unroll
    for (int off = 16; off >= 1; off >>= 1) mx = fmaxf(mx, __shfl_xor(mx, off, 32));
    float sm = 0.f;
    #pragma unroll
    for (int k = 0; k < 16; ++k) {
        int ix = (lane + (k << 5)) * 8 + hh;
        float e = __builtin_amdgcn_exp2f((Ls[ix] - mx) * 1.4426950408889634f);
        Ls[ix] = e; sm += e;
    }
    #pragma unroll
    for (int off = 16; off >= 1; off >>= 1) sm += __shfl_xor(sm, off, 32);
    if (lane == 0) sinv[hh] = __builtin_amdgcn_rcpf(sm);
    __syncthreads();
    for (int i = t; i < 4096; i += 256) Lr[i] = Ls[i] * sinv[i & 7];
}

// ------------------------------------------------- aggregation + residual + store
__global__ __launch_bounds__(256) void kAgg(
    const float* __restrict__ L, const float* __restrict__ vB,
    const void* __restrict__ nfu, void* __restrict__ out,
    const int* __restrict__ flagp)
{
    __shared__ float Ls[8192];             // L rows r0,r1: [2][512 s][8 h]
    const int f32 = flagp[0];
    const int t = threadIdx.x;
    const int r0 = blockIdx.x * 2;

    {
        const float4* Lp4 = reinterpret_cast<const float4*>(L + (((size_t)r0) << 12));
        float4* Ls4 = reinterpret_cast<float4*>(Ls);
        for (int i = t; i < 2048; i += 256) Ls4[i] = Lp4[i];
    }
    __syncthreads();

    if (t >= 240) return;
    const int j0 = 2 * t;
    int hh;
    if (j0 < 128)      hh = j0 >> 4;
    else if (j0 < 320) hh = (j0 - 128) / 24;
    else               hh = (j0 - 320) / 20;

    float a00 = 0.f, a01 = 0.f, a10 = 0.f, a11 = 0.f;
    const float2* vp = reinterpret_cast<const float2*>(vB + j0);  // stride 240 float2
    #pragma unroll 4
    for (int s = 0; s < 512; ++s) {
        float2 v = vp[(size_t)s * 240];
        float w0 = Ls[s * 8 + hh];
        float w1 = Ls[4096 + s * 8 + hh];
        a00 += w0 * v.x; a01 += w0 * v.y;
        a10 += w1 * v.x; a11 += w1 * v.y;
    }

    const size_t o0 = (size_t)r0 * 480 + j0;
    const size_t o1 = o0 + 480;
    float r00 = ldin(nfu, o0, f32) + a00;
    float r01 = ldin(nfu, o0 + 1, f32) + a01;
    float r10 = ldin(nfu, o1, f32) + a10;
    float r11 = ldin(nfu, o1 + 1, f32) + a11;
    if (f32) {
        float* op = (float*)out;
        op[o0] = r00; op[o0 + 1] = r01; op[o1] = r10; op[o1 + 1] = r11;
    } else {
        uint16_t* op = (uint16_t*)out;
        op[o0] = f2bf(r00); op[o0 + 1] = f2bf(r01);
        op[o1] = f2bf(r10); op[o1 + 1] = f2bf(r11);
    }
}

extern "C" void kernel_launch(void* const* d_in, const int* in_sizes, int n_in,
                              void* d_out, int out_size, void* d_ws, size_t ws_size,
                              hipStream_t stream)
{
    (void)in_sizes; (void)n_in; (void)out_size; (void)ws_size;
    const void* nf  = d_in[0];
    const void* eaG = d_in[1];
    const void* shG = d_in[2];

    float* ws = (float*)d_ws;
    float* qS  = ws + QS_OFF;
    float* kT4 = ws + KT_OFF;
    float* vB  = ws + VB_OFF;
    uint32_t* ArecG = (uint32_t*)(ws + ARE_OFF);
    uint32_t* AsndG = (uint32_t*)(ws + ASN_OFF);
    float* Wf  = ws + WF_OFF;
    int* flag  = (int*)(ws + FLAG_OFF);
    float* L   = ws + L_OFF;

    kDet<<<1, 64, 0, stream>>>((const uint32_t*)nf, flag);
    kW<<<1, 256, 0, stream>>>(d_in[12], d_in[13], d_in[14], d_in[15], d_in[16], d_in[17],
                              Wf, flag);
    kA<<<NNODES, 256, 0, stream>>>(nf, d_in[3], d_in[4], d_in[5], d_in[6], d_in[7], d_in[8],
                                   d_in[9], d_in[10], d_in[11], d_in[12],
                                   qS, kT4, vB, ArecG, AsndG, flag);
    kQK<<<dim3(8, 32, 2), 256, 0, stream>>>(qS, kT4, L);
    kB<<<dim3(32, 32), 256, 0, stream>>>(eaG, shG, ArecG, AsndG, Wf, L, flag);
    kSM<<<NNODES, 256, 0, stream>>>(L);
    kAgg<<<256, 256, 0, stream>>>(L, vB, nf, d_out, flag);
}

// Round 8
// 311.065 us; speedup vs baseline: 1.0783x; 1.0783x over previous
//
#include <hip/hip_runtime.h>
#include <hip/hip_bf16.h>
#include <stdint.h>

// ---------------------------------------------------------------------------
// EquivariantAttention on MI355X.  Dtype-adaptive (bf16 or fp32 inputs).
// R7 post-mortem: occupancy pinned ~21% regardless of LDS (grid caps at 50%);
//   Asnd-from-global regressed kB (112->137).  kB is stall-bound.
// R8: (1) revert kB to R6 form (Arec+Asnd LDS, ea direct);
//     (2) L layout -> SoA [h][r][s]: kills the stride-8 scatter in kB's RMW
//     tail, kQK stores, kSM, kAgg staging (all wave-contiguous now);
//     (3) kSM rewritten wave-per-row, shuffle-only.
// ---------------------------------------------------------------------------

#define NNODES 512
#define NDIM   480

// ws layout (4-byte word offsets)
#define QS_OFF    0u         // 512*480 f32 q, per-head layout, CG*ATTN folded
#define KT_OFF    245760u    // k packed: [h(8)][j4(15)][n(512)][4] f32
#define VB_OFF    491520u    // 512*480 f32 v, output-irrep (final) layout
#define ARE_OFF   737280u    // 512*288 u32 (bf16 pairs over o): [n][mi(9)][oc(32)]
#define ASN_OFF   884736u    // 512*288 u32
#define WF_OFF    1032192u   // 8192 f32: W1a[32][64]@0, W2T[64][64]@2048, W3[64][8]@6144, b1@6656, b2@6720, b3@6784
#define FLAG_OFF  1040384u   // flag[0] = 1 if inputs fp32, 0 if bf16
#define L_OFF     1040448u   // L SoA: [h(8)][r(512)][s(512)] f32 (8MB)

__device__ __forceinline__ float bf2f(uint16_t u) {
    return __uint_as_float(((uint32_t)u) << 16);
}
__device__ __forceinline__ uint16_t f2bf(float f) {
    union { __hip_bfloat16 h; uint16_t u; } cv;
    cv.h = __float2bfloat16(f);
    return cv.u;
}
__device__ __forceinline__ float ldin(const void* p, size_t i, int f32) {
    return f32 ? ((const float*)p)[i] : bf2f(((const uint16_t*)p)[i]);
}
// tanh(x) = 1 - 2/(exp(2x)+1)
__device__ __forceinline__ float ftanh(float x) {
    float e = __builtin_amdgcn_exp2f(x * 2.885390081777927f);
    return 1.0f - 2.0f * __builtin_amdgcn_rcpf(e + 1.0f);
}

// ------------------------------------------------- dtype detector
__global__ __launch_bounds__(64) void kDet(const uint32_t* __restrict__ nf,
                                           int* __restrict__ flag)
{
    int t = threadIdx.x;
    uint32_t x = nf[64 + t];
    int e = (x >> 7) & 0xff;
    int good = (x != 0u) && (e >= 100) && (e <= 140);
    unsigned long long m = __ballot(good);
    if (t == 0) flag[0] = (__popcll(m) < 32) ? 1 : 0;
}

// ---------------------------------------------------------------- weights prep
__global__ __launch_bounds__(256) void kW(
    const void* __restrict__ mW1, const void* __restrict__ mb1,
    const void* __restrict__ mW2, const void* __restrict__ mb2,
    const void* __restrict__ mW3, const void* __restrict__ mb3,
    float* __restrict__ Wf, const int* __restrict__ flagp)
{
    const int f32 = flagp[0];
    const int t = threadIdx.x;
    for (int i = t; i < 2048; i += 256) Wf[i] = ldin(mW1, i, f32);      // W1a rows 0..31
    for (int i = t; i < 4096; i += 256) {                               // W2 transposed
        int o2 = i >> 6, ii = i & 63;
        Wf[2048 + i] = ldin(mW2, ii * 64 + o2, f32);
    }
    for (int i = t; i < 512; i += 256) Wf[6144 + i] = ldin(mW3, i, f32);
    if (t < 64) Wf[6656 + t] = ldin(mb1, t, f32);
    if (t < 64) Wf[6720 + t] = ldin(mb2, t, f32);
    if (t < 8)  Wf[6784 + t] = ldin(mb3, t, f32);
}

// ------------------------------------------------- per-node precompute
__global__ __launch_bounds__(256) void kA(
    const void* __restrict__ nfu,
    const void* __restrict__ Wq0, const void* __restrict__ Wq1, const void* __restrict__ Wq2,
    const void* __restrict__ Wk0, const void* __restrict__ Wk1, const void* __restrict__ Wk2,
    const void* __restrict__ Wv0, const void* __restrict__ Wv1, const void* __restrict__ Wv2,
    const void* __restrict__ mW1,
    float* __restrict__ qS, float* __restrict__ kT4, float* __restrict__ vB,
    uint32_t* __restrict__ ArecG, uint32_t* __restrict__ AsndG,
    const int* __restrict__ flagp)
{
    const int f32 = flagp[0];
    const int n = blockIdx.x, t = threadIdx.x;
    __shared__ float nfs[480];
    for (int i = t; i < 480; i += 256) nfs[i] = ldin(nfu, (size_t)n * 480 + i, f32);
    __syncthreads();

    const float e3n0 = 0.08838834764831845f;  // 1/sqrt(128)
    const float e3n1 = 0.125f;                // 1/sqrt(64)
    const float e3n2 = 0.17677669529663687f;  // 1/sqrt(32)
    const float cg0 = 1.0f, cg1 = 0.5773502691896258f, cg2 = 0.4472135954999579f;
    const float attn = 0.1889822365046136f;   // 1/sqrt(28)

    // q/k/v: 3 kinds x 480 outputs
    for (int idx = t; idx < 1440; idx += 256) {
        int kind = idx / 480, rem = idx - kind * 480;
        int l, o, m, mul, d, off, am, qoff;
        if (rem < 128)      { l = 0; o = rem;            m = 0;         mul = 128; d = 1; off = 0;   am = 16; qoff = 0;  }
        else if (rem < 320) { l = 1; int x = rem - 128;  o = x / 3; m = x - o * 3; mul = 64;  d = 3; off = 128; am = 8;  qoff = 16; }
        else                { l = 2; int x = rem - 320;  o = x / 5; m = x - o * 5; mul = 32;  d = 5; off = 320; am = 4;  qoff = 40; }
        const void* W;
        if (kind == 0)      W = (l == 0 ? Wq0 : l == 1 ? Wq1 : Wq2);
        else if (kind == 1) W = (l == 0 ? Wk0 : l == 1 ? Wk1 : Wk2);
        else                W = (l == 0 ? Wv0 : l == 1 ? Wv1 : Wv2);
        float acc = 0.f;
        if (f32) {
            const float* W32 = (const float*)W;
            for (int i = 0; i < mul; ++i) acc += nfs[off + i * d + m] * W32[i * mul + o];
        } else {
            const uint16_t* W16 = (const uint16_t*)W;
            for (int i = 0; i < mul; ++i) acc += nfs[off + i * d + m] * bf2f(W16[i * mul + o]);
        }
        float e3n = (l == 0 ? e3n0 : l == 1 ? e3n1 : e3n2);
        float cg  = (l == 0 ? cg0 : l == 1 ? cg1 : cg2);
        if (kind == 2) {
            vB[(size_t)n * 480 + rem] = acc * e3n;                 // final output layout
        } else {
            int hh = o / am, a = o - hh * am;
            int j = qoff + a * d + m;                              // 0..59 within head
            if (kind == 0) qS[(size_t)n * 480 + hh * 60 + j] = acc * (e3n * cg * attn);
            else           kT4[((size_t)(hh * 15 + (j >> 2)) * 512 + n) * 4 + (j & 3)] = acc * e3n;
        }
    }

    // Arec/Asnd: 2 kinds x 9 mi x 32 o-pairs, packed bf16: [n][mi(9)][oc(32)]
    for (int idx = t; idx < 576; idx += 256) {
        int kind2 = idx / 288, rem = idx - kind2 * 288;
        int mi = rem >> 5, oc = rem & 31;
        int l, m;
        if (mi == 0)     { l = 0; m = 0; }
        else if (mi < 4) { l = 1; m = mi - 1; }
        else             { l = 2; m = mi - 4; }
        int mul = (l == 0 ? 128 : l == 1 ? 64 : 32);
        int d = 2 * l + 1;
        int off = (l == 0 ? 0 : l == 1 ? 128 : 320);
        int base = (kind2 == 0) ? (l == 0 ? 32 : l == 1 ? 160 : 224)
                                : (l == 0 ? 256 : l == 1 ? 384 : 448);
        float a0 = 0.f, a1 = 0.f;
        if (f32) {
            const float* wp = (const float*)mW1 + (size_t)base * 64 + 2 * oc;
            for (int i = 0; i < mul; ++i) {
                float nv = nfs[off + i * d + m];
                a0 += nv * wp[i * 64];
                a1 += nv * wp[i * 64 + 1];
            }
        } else {
            const uint16_t* wp = (const uint16_t*)mW1 + (size_t)base * 64 + 2 * oc;
            for (int i = 0; i < mul; ++i) {
                float nv = nfs[off + i * d + m];
                a0 += nv * bf2f(wp[i * 64]);
                a1 += nv * bf2f(wp[i * 64 + 1]);
            }
        }
        float cg = (l == 0 ? cg0 : l == 1 ? cg1 : cg2);
        a0 *= cg; a1 *= cg;
        uint32_t pk = ((uint32_t)f2bf(a1) << 16) | (uint32_t)f2bf(a0);
        (kind2 ? AsndG : ArecG)[(size_t)n * 288 + mi * 32 + oc] = pk;
    }
}

// ------------------------------------------------- q.k logits -> L (SoA)
// lane = sender; q tile staged in LDS (broadcast); k via kT4 float4 loads.
__global__ __launch_bounds__(256) void kQK(
    const float* __restrict__ qS, const float* __restrict__ kT4,
    float* __restrict__ L)
{
    __shared__ float qL[16 * 240];        // [r16][(h-hb)*60 + j]
    const int t = threadIdx.x;
    const int lane = t & 63, wave = t >> 6;
    const int s0 = blockIdx.x * 64, r0 = blockIdx.y * 16, hb = blockIdx.z * 4;

    {
        float4* qL4 = reinterpret_cast<float4*>(qL);
        for (int i = t; i < 960; i += 256) {
            int rr = i / 60, c4 = i - rr * 60;
            qL4[i] = reinterpret_cast<const float4*>(
                         qS + (size_t)(r0 + rr) * 480 + hb * 60)[c4];
        }
    }
    __syncthreads();

    const int s = s0 + lane;
    const int rw = wave * 4;                         // 4 receivers per wave
    const float4* qL4 = reinterpret_cast<const float4*>(qL);
    const float4* k4  = reinterpret_cast<const float4*>(kT4);

    float acc[16];                                   // [r(4)][h4(4)]
    #pragma unroll
    for (int i = 0; i < 16; ++i) acc[i] = 0.f;

    #pragma unroll
    for (int h4 = 0; h4 < 4; ++h4) {
        const int h = hb + h4;
        #pragma unroll 3
        for (int j4 = 0; j4 < 15; ++j4) {
            float4 kv = k4[(size_t)(h * 15 + j4) * 512 + s];
            #pragma unroll
            for (int r = 0; r < 4; ++r) {
                float4 qv = qL4[(rw + r) * 60 + h4 * 15 + j4];   // wave-broadcast
                acc[r * 4 + h4] += qv.x * kv.x + qv.y * kv.y + qv.z * kv.z + qv.w * kv.w;
            }
        }
    }
    #pragma unroll
    for (int r = 0; r < 4; ++r) {
        #pragma unroll
        for (int h4 = 0; h4 < 4; ++h4) {
            L[(((size_t)(hb + h4)) << 18) + (((size_t)(r0 + rw + r)) << 9) + s] = acc[r * 4 + h4];
        }
    }
}

// ------------------------------------------------- edge MLP (the hot kernel)
// 16x16 edge tile / 256 threads; Arec+Asnd in LDS (R6 form); ea direct global.
__global__ __launch_bounds__(256) void kB(
    const void* __restrict__ eaG, const void* __restrict__ shG,
    const uint32_t* __restrict__ ArecG, const uint32_t* __restrict__ AsndG,
    const float* __restrict__ Wf, float* __restrict__ L,
    const int* __restrict__ flagp)
{
    __shared__ uint32_t ArecS[16 * 292];   // bf16 pairs, row stride 292 dw
    __shared__ uint32_t AsndS[16 * 292];
    const int f32 = flagp[0];
    const int t = threadIdx.x;
    const int s0 = blockIdx.x * 16, r0 = blockIdx.y * 16;

    for (int i = t; i < 16 * 288; i += 256) {
        int row = i / 288, c = i - row * 288;
        ArecS[row * 292 + c] = ArecG[(size_t)(r0 + row) * 288 + c];
        AsndS[row * 292 + c] = AsndG[(size_t)(s0 + row) * 288 + c];
    }

    const int rl = t >> 4, sl = t & 15;
    const int r = r0 + rl, s = s0 + sl;
    const size_t eidx = (((size_t)r) << 9) + s;

    // ea: 32 channels as 16 packed bf16 pairs, loaded directly from global
    uint32_t eaR[16];
    if (f32) {
        const float4* ep = reinterpret_cast<const float4*>((const float*)eaG + eidx * 32);
        #pragma unroll
        for (int i = 0; i < 8; ++i) {
            float4 v = ep[i];
            eaR[2 * i]     = ((uint32_t)f2bf(v.y) << 16) | (uint32_t)f2bf(v.x);
            eaR[2 * i + 1] = ((uint32_t)f2bf(v.w) << 16) | (uint32_t)f2bf(v.z);
        }
    } else {
        const uint4* ep = reinterpret_cast<const uint4*>((const uint32_t*)eaG + eidx * 16);
        #pragma unroll
        for (int i = 0; i < 4; ++i) {
            uint4 v = ep[i];
            eaR[4 * i] = v.x; eaR[4 * i + 1] = v.y; eaR[4 * i + 2] = v.z; eaR[4 * i + 3] = v.w;
        }
    }

    float sh0, sh1, sh2, sh3, sh4, sh5, sh6, sh7, sh8;
    {
        const size_t sb = eidx * 9;
        if (f32) {
            const float* shp = (const float*)shG + sb;
            sh0 = shp[0]; sh1 = shp[1]; sh2 = shp[2]; sh3 = shp[3]; sh4 = shp[4];
            sh5 = shp[5]; sh6 = shp[6]; sh7 = shp[7]; sh8 = shp[8];
        } else {
            const uint16_t* shp = (const uint16_t*)shG + sb;
            sh0 = bf2f(shp[0]); sh1 = bf2f(shp[1]); sh2 = bf2f(shp[2]);
            sh3 = bf2f(shp[3]); sh4 = bf2f(shp[4]); sh5 = bf2f(shp[5]);
            sh6 = bf2f(shp[6]); sh7 = bf2f(shp[7]); sh8 = bf2f(shp[8]);
        }
    }

    float h[64];
    #pragma unroll
    for (int o = 0; o < 64; ++o) h[o] = Wf[6656 + o];   // b1

    __syncthreads();   // ArecS/AsndS ready

    // sh-mix: h[o] += sh[mi]*(Arec[r][mi][o] + Asnd[s][mi][o])
    {
        const int rb = rl * 292, sb = sl * 292;
        #pragma unroll 1
        for (int mi = 0; mi < 9; ++mi) {
            float shv = sh0;
            shv = (mi == 1) ? sh1 : shv;  shv = (mi == 2) ? sh2 : shv;
            shv = (mi == 3) ? sh3 : shv;  shv = (mi == 4) ? sh4 : shv;
            shv = (mi == 5) ? sh5 : shv;  shv = (mi == 6) ? sh6 : shv;
            shv = (mi == 7) ? sh7 : shv;  shv = (mi == 8) ? sh8 : shv;
            const int ro = rb + mi * 32, so = sb + mi * 32;
            #pragma unroll
            for (int oc = 0; oc < 32; ++oc) {
                uint32_t pa = ArecS[ro + oc];
                uint32_t pb = AsndS[so + oc];
                float a0 = __uint_as_float(pa << 16);
                float b0 = __uint_as_float(pb << 16);
                float a1 = __uint_as_float(pa & 0xffff0000u);
                float b1 = __uint_as_float(pb & 0xffff0000u);
                h[2 * oc]     += shv * (a0 + b0);
                h[2 * oc + 1] += shv * (a1 + b1);
            }
        }
    }

    // edge_attr part: h[o] += ea[c]*W1a[c][o], weights wave-uniform (s_load)
    {
        #pragma unroll 1
        for (int cd = 0; cd < 16; ++cd) {
            uint32_t p = eaR[cd];
            float e0 = __uint_as_float(p << 16);
            float e1 = __uint_as_float(p & 0xffff0000u);
            const float* w0 = Wf + (2 * cd) * 64;
            #pragma unroll
            for (int o = 0; o < 64; ++o) h[o] += e0 * w0[o];
            #pragma unroll
            for (int o = 0; o < 64; ++o) h[o] += e1 * w0[64 + o];
        }
    }

    #pragma unroll
    for (int o = 0; o < 64; ++o) h[o] = ftanh(h[o]);

    // layer 2 (rolled over o2, h1 in regs) with fused layer-3 accumulation
    float ew[8];
    #pragma unroll
    for (int hh = 0; hh < 8; ++hh) ew[hh] = Wf[6784 + hh];  // b3
    #pragma unroll 1
    for (int o2 = 0; o2 < 64; ++o2) {
        const float* w2 = Wf + 2048 + o2 * 64;              // W2T row (uniform)
        float ac0 = Wf[6720 + o2], ac1 = 0.f;
        #pragma unroll
        for (int i = 0; i < 64; i += 2) {
            ac0 += h[i] * w2[i];
            ac1 += h[i + 1] * w2[i + 1];
        }
        float t2 = ftanh(ac0 + ac1);
        const float* w3 = Wf + 6144 + o2 * 8;
        #pragma unroll
        for (int hh = 0; hh < 8; ++hh) ew[hh] += t2 * w3[hh];
    }

    // SoA RMW: coalesced per h-plane
    float* Lp = L + (((size_t)r) << 9) + s;
    #pragma unroll
    for (int hh = 0; hh < 8; ++hh) Lp[((size_t)hh) << 18] += ew[hh];
}

// ------------------------------------------------- softmax over senders (SoA, in place)
// wave handles rows (r, h=2w) and (r, h=2w+1); row = contiguous 512 floats.
__global__ __launch_bounds__(256) void kSM(float* __restrict__ L)
{
    const int r = blockIdx.x;
    const int w = threadIdx.x >> 6, lane = threadIdx.x & 63;
    const float C = 1.4426950408889634f;
    #pragma unroll
    for (int hi = 0; hi < 2; ++hi) {
        const int h = w * 2 + hi;
        float4* row4 = reinterpret_cast<float4*>(L + (((size_t)h) << 18) + (((size_t)r) << 9));
        float4 a = row4[lane * 2], b = row4[lane * 2 + 1];
        float m = fmaxf(fmaxf(fmaxf(a.x, a.y), fmaxf(a.z, a.w)),
                        fmaxf(fmaxf(b.x, b.y), fmaxf(b.z, b.w)));
        #pragma unroll
        for (int off = 32; off >= 1; off >>= 1) m = fmaxf(m, __shfl_xor(m, off, 64));
        a.x = __builtin_amdgcn_exp2f((a.x - m) * C);
        a.y = __builtin_amdgcn_exp2f((a.y - m) * C);
        a.z = __builtin_amdgcn_exp2f((a.z - m) * C);
        a.w = __builtin_amdgcn_exp2f((a.w - m) * C);
        b.x = __builtin_amdgcn_exp2f((b.x - m) * C);
        b.y = __builtin_amdgcn_exp2f((b.y - m) * C);
        b.z = __builtin_amdgcn_exp2f((b.z - m) * C);
        b.w = __builtin_amdgcn_exp2f((b.w - m) * C);
        float sm = (a.x + a.y) + (a.z + a.w) + (b.x + b.y) + (b.z + b.w);
        #pragma unroll
        for (int off = 32; off >= 1; off >>= 1) sm += __shfl_xor(sm, off, 64);
        float inv = __builtin_amdgcn_rcpf(sm);
        a.x *= inv; a.y *= inv; a.z *= inv; a.w *= inv;
        b.x *= inv; b.y *= inv; b.z *= inv; b.w *= inv;
        row4[lane * 2] = a; row4[lane * 2 + 1] = b;
    }
}

// ------------------------------------------------- aggregation + residual + store
__global__ __launch_bounds__(256) void kAgg(
    const float* __restrict__ L, const float* __restrict__ vB,
    const void* __restrict__ nfu, void* __restrict__ out,
    const int* __restrict__ flagp)
{
    __shared__ float Ls[8192];             // [rr(2)][s(512)][h(8)]
    const int f32 = flagp[0];
    const int t = threadIdx.x;
    const int r0 = blockIdx.x * 2;

    // stage from SoA planes (coalesced global reads; minor LDS write conflicts OK)
    for (int i = t; i < 8192; i += 256) {
        int rr = i >> 12, rem = i & 4095;
        int h = rem >> 9, s = rem & 511;
        Ls[rr * 4096 + s * 8 + h] =
            L[(((size_t)h) << 18) + (((size_t)(r0 + rr)) << 9) + s];
    }
    __syncthreads();

    if (t >= 240) return;
    const int j0 = 2 * t;
    int hh;
    if (j0 < 128)      hh = j0 >> 4;
    else if (j0 < 320) hh = (j0 - 128) / 24;
    else               hh = (j0 - 320) / 20;

    float a00 = 0.f, a01 = 0.f, a10 = 0.f, a11 = 0.f;
    const float2* vp = reinterpret_cast<const float2*>(vB + j0);  // stride 240 float2
    #pragma unroll 4
    for (int s = 0; s < 512; ++s) {
        float2 v = vp[(size_t)s * 240];
        float w0 = Ls[s * 8 + hh];
        float w1 = Ls[4096 + s * 8 + hh];
        a00 += w0 * v.x; a01 += w0 * v.y;
        a10 += w1 * v.x; a11 += w1 * v.y;
    }

    const size_t o0 = (size_t)r0 * 480 + j0;
    const size_t o1 = o0 + 480;
    float r00 = ldin(nfu, o0, f32) + a00;
    float r01 = ldin(nfu, o0 + 1, f32) + a01;
    float r10 = ldin(nfu, o1, f32) + a10;
    float r11 = ldin(nfu, o1 + 1, f32) + a11;
    if (f32) {
        float* op = (float*)out;
        op[o0] = r00; op[o0 + 1] = r01; op[o1] = r10; op[o1 + 1] = r11;
    } else {
        uint16_t* op = (uint16_t*)out;
        op[o0] = f2bf(r00); op[o0 + 1] = f2bf(r01);
        op[o1] = f2bf(r10); op[o1 + 1] = f2bf(r11);
    }
}

extern "C" void kernel_launch(void* const* d_in, const int* in_sizes, int n_in,
                              void* d_out, int out_size, void* d_ws, size_t ws_size,
                              hipStream_t stream)
{
    (void)in_sizes; (void)n_in; (void)out_size; (void)ws_size;
    const void* nf  = d_in[0];
    const void* eaG = d_in[1];
    const void* shG = d_in[2];

    float* ws = (float*)d_ws;
    float* qS  = ws + QS_OFF;
    float* kT4 = ws + KT_OFF;
    float* vB  = ws + VB_OFF;
    uint32_t* ArecG = (uint32_t*)(ws + ARE_OFF);
    uint32_t* AsndG = (uint32_t*)(ws + ASN_OFF);
    float* Wf  = ws + WF_OFF;
    int* flag  = (int*)(ws + FLAG_OFF);
    float* L   = ws + L_OFF;

    kDet<<<1, 64, 0, stream>>>((const uint32_t*)nf, flag);
    kW<<<1, 256, 0, stream>>>(d_in[12], d_in[13], d_in[14], d_in[15], d_in[16], d_in[17],
                              Wf, flag);
    kA<<<NNODES, 256, 0, stream>>>(nf, d_in[3], d_in[4], d_in[5], d_in[6], d_in[7], d_in[8],
                                   d_in[9], d_in[10], d_in[11], d_in[12],
                                   qS, kT4, vB, ArecG, AsndG, flag);
    kQK<<<dim3(8, 32, 2), 256, 0, stream>>>(qS, kT4, L);
    kB<<<dim3(32, 32), 256, 0, stream>>>(eaG, shG, ArecG, AsndG, Wf, L, flag);
    kSM<<<NNODES, 256, 0, stream>>>(L);
    kAgg<<<256, 256, 0, stream>>>(L, vB, nf, d_out, flag);
}